// Round 6
// baseline (152.103 us; speedup 1.0000x reference)
//
#include <hip/hip_runtime.h>

// RBF-MMD discriminator: B=512 rows, T=128 slabs, C=16, fp32.
// out = E_xx - 2*E_xy over per-slab RBF grams (slab weight 1 for t in {0,127},
// else 2; 254 weighted slab instances).
//
// R6 structure: rounds 2-5 showed the gram main loop is NOT the cost — the
// controllable time (~30 us) was invariant across four different loop
// structures, while every pipe models at <=4 us. The residual is per-dispatch
// wall overhead of the 3-kernel chain. Fix: ONE kernel (+64B memset).
// Each block converts its own A/B rows from x,y into LDS (R4 proved this
// scatter is cheap), runs the R5 pipelined gram loop (verified numerics),
// then f64-atomicAdds its weighted partial; last block (device-scope counter)
// finalizes into d_out.
//
// Split-bf16 MFMA (verified 16x16x32_bf16 layouts):
//   S = A1*B1 + A2*B2, A1=[ahi|alo] B1=[bhi|bhi], A2=[ahi|0] B2=[blo|blo]
//   (lo*lo dropped: ~2^-18 relative, zero-mean).
// Inputs pre-scaled by sqrt(log2 e); entry = exp2(dot') * 2^-gcol * 2^-grow,
// accumulated as fma(exp2(dot'), colscale, acc); row-scale in epilogue.
// Kxx symmetry: strip-pairs q>=a only, q>a weighted 2x (exact).

#define LOG2E 1.4426950408889634f
#define SCALE 1.2011224087864498f   // sqrt(LOG2E)

typedef __attribute__((ext_vector_type(8))) __bf16 bf16x8;
typedef __attribute__((ext_vector_type(4))) float floatx4;

union FragU { uint4 q; unsigned int u[4]; bf16x8 v; };

// 16B-aligned group-padded LDS row offset (dwords): 8 dw/row + 4 dw pad per 4 rows.
static __device__ __forceinline__ int off(int n) { return (n << 3) + ((n >> 2) << 2); }

static __device__ __forceinline__ unsigned short bfbits(__bf16 h) {
    union { __bf16 h; unsigned short s; } u; u.h = h; return u.s;
}
static __device__ __forceinline__ unsigned int packhh(__bf16 a, __bf16 b) {
    return (unsigned int)bfbits(a) | ((unsigned int)bfbits(b) << 16);
}

#define NSLOT 26
#define NBLK  (NSLOT * 128)

// grid (26,128): blockIdx.x = pair slot, blockIdx.y = t.
// slot<16: xy block, a=slot>>2 (A strip of X), q=slot&3 (col strip of Y).
// slot>=16: xx block over triangular (a,q), q>=a, weight 2 if q>a.
// 4 waves; wave w owns A rows a*128 + w*32 (two 16-row tiles).
__global__ __launch_bounds__(256, 4) void mmd_kernel(const float* __restrict__ x,
                                                     const float* __restrict__ y,
                                                     double* __restrict__ acc,
                                                     unsigned int* __restrict__ cnt,
                                                     float* __restrict__ out) {
    __shared__ unsigned int AH[1152], AL[1152], BH[1152], BL[1152];
    __shared__ float csB[128], srg[128];
    __shared__ float red[4];

    const int slot = blockIdx.x;
    const int t    = blockIdx.y;
    const int tid  = threadIdx.x;
    const int w    = tid >> 6;
    const int lane = tid & 63;
    const int quad = lane >> 4;
    const int l15  = lane & 15;
    const int qh   = quad & 1;

    int sa, sq, isxx;
    if (slot < 16) { isxx = 0; sa = slot >> 2; sq = slot & 3; }
    else {
        isxx = 1;
        const int s = slot - 16;
        if      (s < 4) { sa = 0; sq = s; }
        else if (s < 7) { sa = 1; sq = s - 3; }
        else if (s < 9) { sa = 2; sq = s - 5; }
        else            { sa = 3; sq = 3; }
    }

    // ---- staging: threads 0..127 convert A-rows (X), 128..255 B-rows ----
    {
        const int half = tid >> 7;
        const int r    = tid & 127;
        const int grow = (half ? sq : sa) * 128 + r;
        const float4* __restrict__ src4 =
            (half && !isxx) ? (const float4*)y : (const float4*)x;
        const size_t gb = (size_t)grow * 512 + t * 4;
        float4 f0 = src4[gb], f1 = src4[gb + 1], f2 = src4[gb + 2], f3 = src4[gb + 3];
        const float fs[16] = { f0.x, f0.y, f0.z, f0.w, f1.x, f1.y, f1.z, f1.w,
                               f2.x, f2.y, f2.z, f2.w, f3.x, f3.y, f3.z, f3.w };
        float g = 0.f;
        unsigned int hw[8], lw[8];
#pragma unroll
        for (int p = 0; p < 8; ++p) {
            const float v0 = fs[2 * p], v1 = fs[2 * p + 1];
            g += v0 * v0 + v1 * v1;
            const float s0 = v0 * SCALE, s1 = v1 * SCALE;
            const __bf16 h0 = (__bf16)s0, h1 = (__bf16)s1;
            hw[p] = packhh(h0, h1);
            lw[p] = packhh((__bf16)(s0 - (float)h0), (__bf16)(s1 - (float)h1));
        }
        const float gp = 0.5f * LOG2E * g;
        unsigned int* __restrict__ H = half ? BH : AH;
        unsigned int* __restrict__ L = half ? BL : AL;
        const int o = off(r);
        *(uint4*)&H[o]     = make_uint4(hw[0], hw[1], hw[2], hw[3]);
        *(uint4*)&H[o + 4] = make_uint4(hw[4], hw[5], hw[6], hw[7]);
        *(uint4*)&L[o]     = make_uint4(lw[0], lw[1], lw[2], lw[3]);
        *(uint4*)&L[o + 4] = make_uint4(lw[4], lw[5], lw[6], lw[7]);
        if (half) csB[r] = __builtin_amdgcn_exp2f(-gp);
        else      srg[r] = gp;
    }
    __syncthreads();

    // ---- A fragments from LDS: 2 row-tiles per wave ----
    bf16x8 a1f[2], a2f[2];
    {
        FragU z; z.q = make_uint4(0u, 0u, 0u, 0u);
#pragma unroll
        for (int rt = 0; rt < 2; ++rt) {
            const int row = w * 32 + rt * 16 + l15;
            const int rb  = off(row) + qh * 4;
            FragU u;
            u.q = (quad < 2) ? *(const uint4*)&AH[rb] : *(const uint4*)&AL[rb];
            a1f[rt] = u.v;                       // A1 = [ahi | alo]
            a2f[rt] = (quad < 2) ? u.v : z.v;    // A2 = [ahi |  0 ]
        }
    }

    float sum[2][4] = {{0.f, 0.f, 0.f, 0.f}, {0.f, 0.f, 0.f, 0.f}};

    // ---- software-pipelined main loop: MFMA tile jt, exp tile jt-1 ----
    floatx4 accP[2], accC[2];
    float csP;
    {
        const int rb = off(l15) + qh * 4;
        FragU bh, bl;
        bh.q = *(const uint4*)&BH[rb];
        bl.q = *(const uint4*)&BL[rb];
        csP = csB[l15];
        floatx4 zc = {0.f, 0.f, 0.f, 0.f};
        accP[0] = __builtin_amdgcn_mfma_f32_16x16x32_bf16(a1f[0], bh.v, zc, 0, 0, 0);
        accP[0] = __builtin_amdgcn_mfma_f32_16x16x32_bf16(a2f[0], bl.v, accP[0], 0, 0, 0);
        accP[1] = __builtin_amdgcn_mfma_f32_16x16x32_bf16(a1f[1], bh.v, zc, 0, 0, 0);
        accP[1] = __builtin_amdgcn_mfma_f32_16x16x32_bf16(a2f[1], bl.v, accP[1], 0, 0, 0);
    }
#pragma unroll
    for (int jt = 1; jt < 8; ++jt) {
        const int n  = jt * 16 + l15;
        const int rb = off(n) + qh * 4;
        FragU bh, bl;
        bh.q = *(const uint4*)&BH[rb];
        bl.q = *(const uint4*)&BL[rb];
        const float cs = csB[n];
        floatx4 zc = {0.f, 0.f, 0.f, 0.f};
        accC[0] = __builtin_amdgcn_mfma_f32_16x16x32_bf16(a1f[0], bh.v, zc, 0, 0, 0);
        accC[0] = __builtin_amdgcn_mfma_f32_16x16x32_bf16(a2f[0], bl.v, accC[0], 0, 0, 0);
        accC[1] = __builtin_amdgcn_mfma_f32_16x16x32_bf16(a1f[1], bh.v, zc, 0, 0, 0);
        accC[1] = __builtin_amdgcn_mfma_f32_16x16x32_bf16(a2f[1], bl.v, accC[1], 0, 0, 0);
#pragma unroll
        for (int rt = 0; rt < 2; ++rt)
#pragma unroll
            for (int r = 0; r < 4; ++r)
                sum[rt][r] = fmaf(__builtin_amdgcn_exp2f(accP[rt][r]), csP, sum[rt][r]);
        accP[0] = accC[0];
        accP[1] = accC[1];
        csP = cs;
    }
#pragma unroll
    for (int rt = 0; rt < 2; ++rt)
#pragma unroll
        for (int r = 0; r < 4; ++r)
            sum[rt][r] = fmaf(__builtin_amdgcn_exp2f(accP[rt][r]), csP, sum[rt][r]);

    // ---- epilogue: row-scale, block reduce, device-scope f64 accumulate ----
    float tot = 0.f;
#pragma unroll
    for (int rt = 0; rt < 2; ++rt)
#pragma unroll
        for (int r = 0; r < 4; ++r) {
            const float rs = __builtin_amdgcn_exp2f(-srg[w * 32 + rt * 16 + quad * 4 + r]);
            tot = fmaf(sum[rt][r], rs, tot);
        }
    for (int o = 32; o > 0; o >>= 1) tot += __shfl_down(tot, o, 64);
    if (lane == 0) red[w] = tot;
    __syncthreads();
    if (tid == 0) {
        float wt = (t == 0 || t == 127) ? 1.f : 2.f;
        if (isxx && sq > sa) wt *= 2.f;   // symmetric off-diag strip-pair
        const double part = (double)(wt * (red[0] + red[1] + red[2] + red[3]));
        atomicAdd(&acc[isxx], part);      // acc[0]=xy sum, acc[1]=xx sum
        __threadfence();
        const unsigned int old = atomicAdd(cnt, 1u);
        if (old == NBLK - 1) {
            const double sxy = __hip_atomic_load(&acc[0], __ATOMIC_RELAXED,
                                                 __HIP_MEMORY_SCOPE_AGENT);
            const double sxx = __hip_atomic_load(&acc[1], __ATOMIC_RELAXED,
                                                 __HIP_MEMORY_SCOPE_AGENT);
            // diagonal entries (~1.0 each) included in sxx: subtract 254*512
            const double e1 = (sxx - 254.0 * 512.0) / (254.0 * 512.0 * 511.0);
            const double e2 = sxy / (254.0 * 512.0 * 512.0);
            out[0] = (float)(e1 - 2.0 * e2);
        }
    }
}

extern "C" void kernel_launch(void* const* d_in, const int* in_sizes, int n_in,
                              void* d_out, int out_size, void* d_ws, size_t ws_size,
                              hipStream_t stream) {
    (void)in_sizes; (void)n_in; (void)out_size; (void)ws_size;
    const float* x = (const float*)d_in[0];
    const float* y = (const float*)d_in[1];
    float* out = (float*)d_out;
    double* acc = (double*)d_ws;                         // acc[0]=xy, acc[1]=xx
    unsigned int* cnt = (unsigned int*)((char*)d_ws + 16);

    hipMemsetAsync(d_ws, 0, 64, stream);                 // zero acc + counter
    mmd_kernel<<<dim3(NSLOT, 128), dim3(256), 0, stream>>>(x, y, acc, cnt, out);
}

// Round 7
// 74.473 us; speedup vs baseline: 2.0424x; 2.0424x over previous
//
#include <hip/hip_runtime.h>

// RBF-MMD discriminator: B=512 rows, T=128 slabs, C=16, fp32.
// out = E_xx - 2*E_xy over per-slab RBF grams (slab weight 1 for t in {0,127},
// else 2; 254 weighted slab instances).
//
// R7 structure: R6's profile showed the fused kernel at 100 us with ALL pipes
// idle (VALU 10%, MFMA 2.5%, HBM 2.8%, occ 30%) — the same-address f64
// atomicAdd + __threadfence per block serialized the whole grid at the owning
// L2 and blocked retirement. Fix: NO atomics — each block plain-stores its
// weighted partial to a distinct d_ws slot (R5's verified scheme); a tiny
// finalize kernel reduces in f64. Everything else is R6's fused body
// (in-block conversion + verified pipelined gram loop).
//
// Split-bf16 MFMA (verified 16x16x32_bf16 layouts):
//   S = A1*B1 + A2*B2, A1=[ahi|alo] B1=[bhi|bhi], A2=[ahi|0] B2=[blo|blo]
//   (lo*lo dropped: ~2^-18 relative, zero-mean).
// Inputs pre-scaled by sqrt(log2 e); entry = exp2(dot') * 2^-gcol * 2^-grow,
// accumulated as fma(exp2(dot'), colscale, acc); row-scale in epilogue.
// Kxx symmetry: strip-pairs q>=a only, q>a weighted 2x (exact).

#define LOG2E 1.4426950408889634f
#define SCALE 1.2011224087864498f   // sqrt(LOG2E)

typedef __attribute__((ext_vector_type(8))) __bf16 bf16x8;
typedef __attribute__((ext_vector_type(4))) float floatx4;

union FragU { uint4 q; unsigned int u[4]; bf16x8 v; };

// 16B-aligned group-padded LDS row offset (dwords): 8 dw/row + 4 dw pad per 4 rows.
static __device__ __forceinline__ int off(int n) { return (n << 3) + ((n >> 2) << 2); }

static __device__ __forceinline__ unsigned short bfbits(__bf16 h) {
    union { __bf16 h; unsigned short s; } u; u.h = h; return u.s;
}
static __device__ __forceinline__ unsigned int packhh(__bf16 a, __bf16 b) {
    return (unsigned int)bfbits(a) | ((unsigned int)bfbits(b) << 16);
}

#define NSLOT 26

// grid (26,128): blockIdx.x = pair slot, blockIdx.y = t.
// slot<16: xy block, a=slot>>2 (A strip of X), q=slot&3 (col strip of Y).
// slot>=16: xx block over triangular (a,q), q>=a, weight 2 if q>a.
// 4 waves; wave w owns A rows a*128 + w*32 (two 16-row tiles).
// Partial stored at part[t*16+slot] (xy) or part[2048 + t*10 + slot-16] (xx).
__global__ __launch_bounds__(256, 8) void mmd_kernel(const float* __restrict__ x,
                                                     const float* __restrict__ y,
                                                     float* __restrict__ part) {
    __shared__ unsigned int AH[1152], AL[1152], BH[1152], BL[1152];
    __shared__ float csB[128], srg[128];
    __shared__ float red[4];

    const int slot = blockIdx.x;
    const int t    = blockIdx.y;
    const int tid  = threadIdx.x;
    const int w    = tid >> 6;
    const int lane = tid & 63;
    const int quad = lane >> 4;
    const int l15  = lane & 15;
    const int qh   = quad & 1;

    int sa, sq, isxx;
    if (slot < 16) { isxx = 0; sa = slot >> 2; sq = slot & 3; }
    else {
        isxx = 1;
        const int s = slot - 16;
        if      (s < 4) { sa = 0; sq = s; }
        else if (s < 7) { sa = 1; sq = s - 3; }
        else if (s < 9) { sa = 2; sq = s - 5; }
        else            { sa = 3; sq = 3; }
    }

    // ---- staging: threads 0..127 convert A-rows (X), 128..255 B-rows ----
    {
        const int half = tid >> 7;
        const int r    = tid & 127;
        const int grow = (half ? sq : sa) * 128 + r;
        const float4* __restrict__ src4 =
            (half && !isxx) ? (const float4*)y : (const float4*)x;
        const size_t gb = (size_t)grow * 512 + t * 4;
        float4 f0 = src4[gb], f1 = src4[gb + 1], f2 = src4[gb + 2], f3 = src4[gb + 3];
        const float fs[16] = { f0.x, f0.y, f0.z, f0.w, f1.x, f1.y, f1.z, f1.w,
                               f2.x, f2.y, f2.z, f2.w, f3.x, f3.y, f3.z, f3.w };
        float g = 0.f;
        unsigned int hw[8], lw[8];
#pragma unroll
        for (int p = 0; p < 8; ++p) {
            const float v0 = fs[2 * p], v1 = fs[2 * p + 1];
            g += v0 * v0 + v1 * v1;
            const float s0 = v0 * SCALE, s1 = v1 * SCALE;
            const __bf16 h0 = (__bf16)s0, h1 = (__bf16)s1;
            hw[p] = packhh(h0, h1);
            lw[p] = packhh((__bf16)(s0 - (float)h0), (__bf16)(s1 - (float)h1));
        }
        const float gp = 0.5f * LOG2E * g;
        unsigned int* __restrict__ H = half ? BH : AH;
        unsigned int* __restrict__ L = half ? BL : AL;
        const int o = off(r);
        *(uint4*)&H[o]     = make_uint4(hw[0], hw[1], hw[2], hw[3]);
        *(uint4*)&H[o + 4] = make_uint4(hw[4], hw[5], hw[6], hw[7]);
        *(uint4*)&L[o]     = make_uint4(lw[0], lw[1], lw[2], lw[3]);
        *(uint4*)&L[o + 4] = make_uint4(lw[4], lw[5], lw[6], lw[7]);
        if (half) csB[r] = __builtin_amdgcn_exp2f(-gp);
        else      srg[r] = gp;
    }
    __syncthreads();

    // ---- A fragments from LDS: 2 row-tiles per wave ----
    bf16x8 a1f[2], a2f[2];
    {
        FragU z; z.q = make_uint4(0u, 0u, 0u, 0u);
#pragma unroll
        for (int rt = 0; rt < 2; ++rt) {
            const int row = w * 32 + rt * 16 + l15;
            const int rb  = off(row) + qh * 4;
            FragU u;
            u.q = (quad < 2) ? *(const uint4*)&AH[rb] : *(const uint4*)&AL[rb];
            a1f[rt] = u.v;                       // A1 = [ahi | alo]
            a2f[rt] = (quad < 2) ? u.v : z.v;    // A2 = [ahi |  0 ]
        }
    }

    float sum[2][4] = {{0.f, 0.f, 0.f, 0.f}, {0.f, 0.f, 0.f, 0.f}};

    // ---- software-pipelined main loop: MFMA tile jt, exp tile jt-1 ----
    floatx4 accP[2], accC[2];
    float csP;
    {
        const int rb = off(l15) + qh * 4;
        FragU bh, bl;
        bh.q = *(const uint4*)&BH[rb];
        bl.q = *(const uint4*)&BL[rb];
        csP = csB[l15];
        floatx4 zc = {0.f, 0.f, 0.f, 0.f};
        accP[0] = __builtin_amdgcn_mfma_f32_16x16x32_bf16(a1f[0], bh.v, zc, 0, 0, 0);
        accP[0] = __builtin_amdgcn_mfma_f32_16x16x32_bf16(a2f[0], bl.v, accP[0], 0, 0, 0);
        accP[1] = __builtin_amdgcn_mfma_f32_16x16x32_bf16(a1f[1], bh.v, zc, 0, 0, 0);
        accP[1] = __builtin_amdgcn_mfma_f32_16x16x32_bf16(a2f[1], bl.v, accP[1], 0, 0, 0);
    }
#pragma unroll
    for (int jt = 1; jt < 8; ++jt) {
        const int n  = jt * 16 + l15;
        const int rb = off(n) + qh * 4;
        FragU bh, bl;
        bh.q = *(const uint4*)&BH[rb];
        bl.q = *(const uint4*)&BL[rb];
        const float cs = csB[n];
        floatx4 zc = {0.f, 0.f, 0.f, 0.f};
        accC[0] = __builtin_amdgcn_mfma_f32_16x16x32_bf16(a1f[0], bh.v, zc, 0, 0, 0);
        accC[0] = __builtin_amdgcn_mfma_f32_16x16x32_bf16(a2f[0], bl.v, accC[0], 0, 0, 0);
        accC[1] = __builtin_amdgcn_mfma_f32_16x16x32_bf16(a1f[1], bh.v, zc, 0, 0, 0);
        accC[1] = __builtin_amdgcn_mfma_f32_16x16x32_bf16(a2f[1], bl.v, accC[1], 0, 0, 0);
#pragma unroll
        for (int rt = 0; rt < 2; ++rt)
#pragma unroll
            for (int r = 0; r < 4; ++r)
                sum[rt][r] = fmaf(__builtin_amdgcn_exp2f(accP[rt][r]), csP, sum[rt][r]);
        accP[0] = accC[0];
        accP[1] = accC[1];
        csP = cs;
    }
#pragma unroll
    for (int rt = 0; rt < 2; ++rt)
#pragma unroll
        for (int r = 0; r < 4; ++r)
            sum[rt][r] = fmaf(__builtin_amdgcn_exp2f(accP[rt][r]), csP, sum[rt][r]);

    // ---- epilogue: row-scale, block reduce, plain store to distinct slot ----
    float tot = 0.f;
#pragma unroll
    for (int rt = 0; rt < 2; ++rt)
#pragma unroll
        for (int r = 0; r < 4; ++r) {
            const float rs = __builtin_amdgcn_exp2f(-srg[w * 32 + rt * 16 + quad * 4 + r]);
            tot = fmaf(sum[rt][r], rs, tot);
        }
    for (int o = 32; o > 0; o >>= 1) tot += __shfl_down(tot, o, 64);
    if (lane == 0) red[w] = tot;
    __syncthreads();
    if (tid == 0) {
        float wt = (t == 0 || t == 127) ? 1.f : 2.f;
        if (isxx && sq > sa) wt *= 2.f;   // symmetric off-diag strip-pair
        const int idx = isxx ? (2048 + t * 10 + (slot - 16)) : (t * 16 + slot);
        part[idx] = wt * (red[0] + red[1] + red[2] + red[3]);
    }
}

__global__ __launch_bounds__(256) void finalize_kernel(const float* __restrict__ part,
                                                       float* __restrict__ out) {
    const int tid = threadIdx.x;
    double vxy = 0.0, vxx = 0.0;
#pragma unroll
    for (int k = 0; k < 8; ++k)  vxy += (double)part[tid + 256 * k];      // [0,2048)
#pragma unroll
    for (int k = 8; k < 13; ++k) vxx += (double)part[tid + 256 * k];      // [2048,3328)
    for (int o = 32; o > 0; o >>= 1) {
        vxx += __shfl_down(vxx, o, 64);
        vxy += __shfl_down(vxy, o, 64);
    }
    __shared__ double red[8];
    const int wid = tid >> 6;
    if ((tid & 63) == 0) { red[wid] = vxx; red[4 + wid] = vxy; }
    __syncthreads();
    if (tid == 0) {
        double sxx = red[0] + red[1] + red[2] + red[3];
        double sxy = red[4] + red[5] + red[6] + red[7];
        // diagonal entries (~1.0 each) included in sxx: subtract 254*512
        double e1 = (sxx - 254.0 * 512.0) / (254.0 * 512.0 * 511.0);
        double e2 = sxy / (254.0 * 512.0 * 512.0);
        out[0] = (float)(e1 - 2.0 * e2);
    }
}

extern "C" void kernel_launch(void* const* d_in, const int* in_sizes, int n_in,
                              void* d_out, int out_size, void* d_ws, size_t ws_size,
                              hipStream_t stream) {
    (void)in_sizes; (void)n_in; (void)out_size; (void)ws_size;
    const float* x = (const float*)d_in[0];
    const float* y = (const float*)d_in[1];
    float* out  = (float*)d_out;
    float* part = (float*)d_ws;   // 3328 floats: [0,2048) xy, [2048,3328) xx

    mmd_kernel<<<dim3(NSLOT, 128), dim3(256), 0, stream>>>(x, y, part);
    finalize_kernel<<<dim3(1), dim3(256), 0, stream>>>(part, out);
}

// Round 8
// 71.788 us; speedup vs baseline: 2.1188x; 1.0374x over previous
//
#include <hip/hip_runtime.h>

// RBF-MMD discriminator: B=512 rows, T=128 slabs, C=16, fp32.
// out = E_xx - 2*E_xy over per-slab RBF grams (slab weight 1 for t in {0,127},
// else 2; 254 weighted slab instances).
//
// R8 structure: per-entry cost has been ~1 SIMD-cyc across ALL structures
// (R4 0.88, R7 1.2) — scales with tiles, not staging/access. So: halve the
// tile cost. Pure-bf16 dot (no hi/lo split): error budget — bf16 noise
// sigma~0.023 in the exponent -> per-entry ~1.6% zero-mean, bias ~1.3e-4
// relative, diag-correction residual ~2.6e-7 absolute; all >=10x inside the
// 3.05e-6 threshold. K-slots 16..31 of the 16x16x32 MFMA are then free:
// fold -g_col in as hi+lo bf16 channels (k16,k17) against A=1.0 constants,
// so acc = log2e*(dot - |col|^2/2) directly; per-entry work = exp2 + add.
// Row-scale 2^-g_row epilogue kept from R7 (verified).
// Kxx symmetry: strip-pairs q>=a only, q>a weighted 2x (exact).

#define LOG2E 1.4426950408889634f
#define SCALE 1.2011224087864498f   // sqrt(LOG2E)

typedef __attribute__((ext_vector_type(8))) __bf16 bf16x8;
typedef __attribute__((ext_vector_type(4))) float floatx4;

union FragU { uint4 q; unsigned int u[4]; bf16x8 v; };

// 16B-aligned group-padded LDS row offset (dwords): 8 dw/row + 4 dw pad per 4 rows.
static __device__ __forceinline__ int off(int n) { return (n << 3) + ((n >> 2) << 2); }

static __device__ __forceinline__ unsigned short bfbits(__bf16 h) {
    union { __bf16 h; unsigned short s; } u; u.h = h; return u.s;
}
static __device__ __forceinline__ unsigned int packhh(__bf16 a, __bf16 b) {
    return (unsigned int)bfbits(a) | ((unsigned int)bfbits(b) << 16);
}

#define NSLOT 26
#define ONEONE 0x3F803F80u   // packed bf16 {1.0, 1.0}

// grid (26,128): blockIdx.x = pair slot, blockIdx.y = t.
// slot<16: xy block, a=slot>>2 (A strip of X), q=slot&3 (col strip of Y).
// slot>=16: xx block over triangular (a,q), q>=a, weight 2 if q>a.
// 4 waves; wave w owns A rows a*128 + w*32 (two 16-row tiles).
__global__ __launch_bounds__(256, 8) void mmd_kernel(const float* __restrict__ x,
                                                     const float* __restrict__ y,
                                                     float* __restrict__ part) {
    __shared__ unsigned int AH[1152], BH[1152];
    __shared__ unsigned int BG[512];      // per B-row: {pack(-ghi,-glo),0,0,0}
    __shared__ float srg[128];            // g per A-row
    __shared__ unsigned int zero4[4];
    __shared__ float red[4];

    const int slot = blockIdx.x;
    const int t    = blockIdx.y;
    const int tid  = threadIdx.x;
    const int w    = tid >> 6;
    const int lane = tid & 63;
    const int quad = lane >> 4;
    const int l15  = lane & 15;
    const int qh   = quad & 1;

    int sa, sq, isxx;
    if (slot < 16) { isxx = 0; sa = slot >> 2; sq = slot & 3; }
    else {
        isxx = 1;
        const int s = slot - 16;
        if      (s < 4) { sa = 0; sq = s; }
        else if (s < 7) { sa = 1; sq = s - 3; }
        else if (s < 9) { sa = 2; sq = s - 5; }
        else            { sa = 3; sq = 3; }
    }

    if (tid == 0) { zero4[0] = 0u; zero4[1] = 0u; zero4[2] = 0u; zero4[3] = 0u; }

    // ---- staging: threads 0..127 convert A-rows (X), 128..255 B-rows ----
    {
        const int half = tid >> 7;
        const int r    = tid & 127;
        const int grow = (half ? sq : sa) * 128 + r;
        const float4* __restrict__ src4 =
            (half && !isxx) ? (const float4*)y : (const float4*)x;
        const size_t gb = (size_t)grow * 512 + t * 4;
        float4 f0 = src4[gb], f1 = src4[gb + 1], f2 = src4[gb + 2], f3 = src4[gb + 3];
        const float fs[16] = { f0.x, f0.y, f0.z, f0.w, f1.x, f1.y, f1.z, f1.w,
                               f2.x, f2.y, f2.z, f2.w, f3.x, f3.y, f3.z, f3.w };
        float g = 0.f;
        unsigned int hw[8];
#pragma unroll
        for (int p = 0; p < 8; ++p) {
            const float v0 = fs[2 * p], v1 = fs[2 * p + 1];
            g += v0 * v0 + v1 * v1;
            hw[p] = packhh((__bf16)(v0 * SCALE), (__bf16)(v1 * SCALE));
        }
        const float gp = 0.5f * LOG2E * g;   // log2-domain column/row norm
        unsigned int* __restrict__ H = half ? BH : AH;
        const int o = off(r);
        *(uint4*)&H[o]     = make_uint4(hw[0], hw[1], hw[2], hw[3]);
        *(uint4*)&H[o + 4] = make_uint4(hw[4], hw[5], hw[6], hw[7]);
        if (half) {
            // -g as hi+lo bf16 (residual ~6e-5 in the exponent)
            const __bf16 nh = (__bf16)(-gp);
            const __bf16 nl = (__bf16)(-(gp + (float)nh));
            *(uint4*)&BG[r * 4] = make_uint4(packhh(nh, nl), 0u, 0u, 0u);
        } else {
            srg[r] = gp;
        }
    }
    __syncthreads();

    // ---- A fragments: quads 0/1 = hi data (k0..15); quad 2 = {1,1,0..}
    //      (k16,k17 multiply B's -g channels); quad 3 = zeros ----
    bf16x8 a1f[2];
    {
#pragma unroll
        for (int rt = 0; rt < 2; ++rt) {
            FragU u;
            if (quad < 2) {
                const int row = w * 32 + rt * 16 + l15;
                u.q = *(const uint4*)&AH[off(row) + qh * 4];
            } else {
                u.q = make_uint4((quad == 2) ? ONEONE : 0u, 0u, 0u, 0u);
            }
            a1f[rt] = u.v;
        }
    }

    // per-lane B-fragment base pointer + per-jt stride (dwords)
    const unsigned int* bptr;
    int bstride;
    if (quad < 2)      { bptr = &BH[off(l15) + qh * 4]; bstride = 144; }
    else if (quad == 2){ bptr = &BG[l15 * 4];           bstride = 64;  }
    else               { bptr = &zero4[0];              bstride = 0;   }

    float sum[2][4] = {{0.f, 0.f, 0.f, 0.f}, {0.f, 0.f, 0.f, 0.f}};

    // ---- software-pipelined main loop: MFMA tile jt, exp tile jt-1 ----
    floatx4 accP[2], accC[2];
    {
        FragU b; b.q = *(const uint4*)bptr; bptr += bstride;
        floatx4 zc = {0.f, 0.f, 0.f, 0.f};
        accP[0] = __builtin_amdgcn_mfma_f32_16x16x32_bf16(a1f[0], b.v, zc, 0, 0, 0);
        accP[1] = __builtin_amdgcn_mfma_f32_16x16x32_bf16(a1f[1], b.v, zc, 0, 0, 0);
    }
#pragma unroll
    for (int jt = 1; jt < 8; ++jt) {
        FragU b; b.q = *(const uint4*)bptr; bptr += bstride;
        floatx4 zc = {0.f, 0.f, 0.f, 0.f};
        accC[0] = __builtin_amdgcn_mfma_f32_16x16x32_bf16(a1f[0], b.v, zc, 0, 0, 0);
        accC[1] = __builtin_amdgcn_mfma_f32_16x16x32_bf16(a1f[1], b.v, zc, 0, 0, 0);
#pragma unroll
        for (int rt = 0; rt < 2; ++rt)
#pragma unroll
            for (int r = 0; r < 4; ++r)
                sum[rt][r] += __builtin_amdgcn_exp2f(accP[rt][r]);
        accP[0] = accC[0];
        accP[1] = accC[1];
    }
#pragma unroll
    for (int rt = 0; rt < 2; ++rt)
#pragma unroll
        for (int r = 0; r < 4; ++r)
            sum[rt][r] += __builtin_amdgcn_exp2f(accP[rt][r]);

    // ---- epilogue: row-scale by 2^-g_row, block reduce, store to slot ----
    float tot = 0.f;
#pragma unroll
    for (int rt = 0; rt < 2; ++rt)
#pragma unroll
        for (int r = 0; r < 4; ++r) {
            const float rs = __builtin_amdgcn_exp2f(-srg[w * 32 + rt * 16 + quad * 4 + r]);
            tot = fmaf(sum[rt][r], rs, tot);
        }
    for (int o = 32; o > 0; o >>= 1) tot += __shfl_down(tot, o, 64);
    if (lane == 0) red[w] = tot;
    __syncthreads();
    if (tid == 0) {
        float wt = (t == 0 || t == 127) ? 1.f : 2.f;
        if (isxx && sq > sa) wt *= 2.f;   // symmetric off-diag strip-pair
        const int idx = isxx ? (2048 + t * 10 + (slot - 16)) : (t * 16 + slot);
        part[idx] = wt * (red[0] + red[1] + red[2] + red[3]);
    }
}

__global__ __launch_bounds__(256) void finalize_kernel(const float* __restrict__ part,
                                                       float* __restrict__ out) {
    const int tid = threadIdx.x;
    double vxy = 0.0, vxx = 0.0;
#pragma unroll
    for (int k = 0; k < 8; ++k)  vxy += (double)part[tid + 256 * k];      // [0,2048)
#pragma unroll
    for (int k = 8; k < 13; ++k) vxx += (double)part[tid + 256 * k];      // [2048,3328)
    for (int o = 32; o > 0; o >>= 1) {
        vxx += __shfl_down(vxx, o, 64);
        vxy += __shfl_down(vxy, o, 64);
    }
    __shared__ double red[8];
    const int wid = tid >> 6;
    if ((tid & 63) == 0) { red[wid] = vxx; red[4 + wid] = vxy; }
    __syncthreads();
    if (tid == 0) {
        double sxx = red[0] + red[1] + red[2] + red[3];
        double sxy = red[4] + red[5] + red[6] + red[7];
        // diagonal entries (~1.0 each) included in sxx: subtract 254*512
        double e1 = (sxx - 254.0 * 512.0) / (254.0 * 512.0 * 511.0);
        double e2 = sxy / (254.0 * 512.0 * 512.0);
        out[0] = (float)(e1 - 2.0 * e2);
    }
}

extern "C" void kernel_launch(void* const* d_in, const int* in_sizes, int n_in,
                              void* d_out, int out_size, void* d_ws, size_t ws_size,
                              hipStream_t stream) {
    (void)in_sizes; (void)n_in; (void)out_size; (void)ws_size;
    const float* x = (const float*)d_in[0];
    const float* y = (const float*)d_in[1];
    float* out  = (float*)d_out;
    float* part = (float*)d_ws;   // 3328 floats: [0,2048) xy, [2048,3328) xx

    mmd_kernel<<<dim3(NSLOT, 128), dim3(256), 0, stream>>>(x, y, part);
    finalize_kernel<<<dim3(1), dim3(256), 0, stream>>>(part, out);
}